// Round 1
// baseline (309.350 us; speedup 1.0000x reference)
//
#include <hip/hip_runtime.h>

// ---------------------------------------------------------------------------
// GCN forward: 2-layer, fused normalization.
//   deg[d] = in_degree(d) + 1 (self loop);  dinv = 1/sqrt(deg)
//   g1 = dinv .* (x @ W1)
//   h  = relu(dinv[d] * (sum_{s->d} g1[s] + g1[d]) + b1)
//   g2 = dinv .* (h @ W2)          (fused into agg1 epilogue, h never stored)
//   z  = dinv[d] * (sum_{s->d} g2[s] + g2[d]) + b2
//   out = log_softmax(z)
// CSR built on device each call (deterministic work; float sum order may vary
// within rounding, well inside threshold).
// ---------------------------------------------------------------------------

#define DIM 128

// edge_index may be int32 (JAX x64 disabled) or int64. Detect: int64 view has
// zero high words at odd int32 positions.
__global__ void detect_kernel(const int* __restrict__ ei, int e, int* flag) {
    if (blockIdx.x == 0 && threadIdx.x == 0) {
        int ok64 = 1;
        for (int i = 0; i < 32; ++i) {
            if (ei[2 * i + 1] != 0) { ok64 = 0; break; }
        }
        *flag = ok64;
    }
}

__device__ __forceinline__ int load_idx(const int* ei, long long pos, int is64) {
    if (is64) return (int)((const long long*)ei)[pos];
    return ei[pos];
}

__global__ void init_counts(int* counts, int* cursor, int n) {
    int i = blockIdx.x * blockDim.x + threadIdx.x;
    if (i < n) { counts[i] = 0; cursor[i] = 0; }
}

__global__ void count_kernel(const int* __restrict__ ei, const int* __restrict__ flag,
                             int* counts, int e) {
    int i = blockIdx.x * blockDim.x + threadIdx.x;
    if (i >= e) return;
    int is64 = *flag;
    int d = load_idx(ei, (long long)e + i, is64);
    atomicAdd(&counts[d], 1);
}

// single-block exclusive scan over counts -> row_ptr (n up to ~50k)
__global__ void scan_kernel(const int* __restrict__ counts, int* __restrict__ row_ptr, int n) {
    __shared__ int lds[1024];
    int t = threadIdx.x;
    int chunk = (n + 1023) / 1024;
    int begin = t * chunk;
    int end = begin + chunk; if (end > n) end = n;
    int s = 0;
    for (int i = begin; i < end; ++i) s += counts[i];
    lds[t] = s;
    __syncthreads();
    for (int off = 1; off < 1024; off <<= 1) {
        int v = (t >= off) ? lds[t - off] : 0;
        __syncthreads();
        lds[t] += v;
        __syncthreads();
    }
    int excl = (t == 0) ? 0 : lds[t - 1];
    int run = excl;
    for (int i = begin; i < end; ++i) { row_ptr[i] = run; run += counts[i]; }
    if (end == n) row_ptr[n] = run;   // all tail threads write the same total
}

__global__ void dinv_kernel(const int* __restrict__ counts, float* __restrict__ dinv, int n) {
    int i = blockIdx.x * blockDim.x + threadIdx.x;
    if (i < n) dinv[i] = 1.0f / sqrtf((float)(counts[i] + 1));
}

__global__ void fill_kernel(const int* __restrict__ ei, const int* __restrict__ flag,
                            const int* __restrict__ row_ptr, int* cursor,
                            int* __restrict__ col_idx, int e) {
    int i = blockIdx.x * blockDim.x + threadIdx.x;
    if (i >= e) return;
    int is64 = *flag;
    int s = load_idx(ei, i, is64);
    int d = load_idx(ei, (long long)e + i, is64);
    int pos = row_ptr[d] + atomicAdd(&cursor[d], 1);
    col_idx[pos] = s;
}

// g1[row][c] = dinv[row] * sum_k x[row][k] * W1[k][c]
// 128 threads (one per output column), 16 rows per block.
#define G1_ROWS 16
__global__ void gemm1_kernel(const float* __restrict__ x, const float* __restrict__ W1,
                             const float* __restrict__ dinv, float* __restrict__ g1, int n) {
    __shared__ float4 xs[G1_ROWS][DIM / 4];
    int t = threadIdx.x;  // column 0..127
    int row0 = blockIdx.x * G1_ROWS;
    for (int r = 0; r < G1_ROWS; ++r) {
        int row = row0 + r;
        float v = 0.f, dv = 0.f;
        if (row < n) { v = x[(long long)row * DIM + t]; dv = dinv[row]; }
        ((float*)&xs[r][0])[t] = v * dv;
    }
    __syncthreads();
    float acc[G1_ROWS];
#pragma unroll
    for (int r = 0; r < G1_ROWS; ++r) acc[r] = 0.f;
    for (int k4 = 0; k4 < DIM / 4; ++k4) {
        float w0 = W1[(k4 * 4 + 0) * DIM + t];
        float w1 = W1[(k4 * 4 + 1) * DIM + t];
        float w2 = W1[(k4 * 4 + 2) * DIM + t];
        float w3 = W1[(k4 * 4 + 3) * DIM + t];
#pragma unroll
        for (int r = 0; r < G1_ROWS; ++r) {
            float4 xv = xs[r][k4];   // wave-uniform address -> broadcast
            acc[r] = fmaf(xv.x, w0, acc[r]);
            acc[r] = fmaf(xv.y, w1, acc[r]);
            acc[r] = fmaf(xv.z, w2, acc[r]);
            acc[r] = fmaf(xv.w, w3, acc[r]);
        }
    }
    for (int r = 0; r < G1_ROWS; ++r) {
        int row = row0 + r;
        if (row < n) g1[(long long)row * DIM + t] = acc[r];
    }
}

// One block (128 threads) per dst node: aggregate g1 over in-edges, apply
// relu(dinv*acc + b1), then fused GEMM2 (128 -> 2) + dinv scale into g2.
__global__ void agg1_kernel(const float* __restrict__ g1, const int* __restrict__ row_ptr,
                            const int* __restrict__ col_idx, const float* __restrict__ dinv,
                            const float* __restrict__ b1, const float* __restrict__ W2,
                            float* __restrict__ g2, int n) {
    int d = blockIdx.x;
    if (d >= n) return;
    int t = threadIdx.x;
    float acc = g1[(long long)d * DIM + t];   // self loop
    int beg = row_ptr[d], end = row_ptr[d + 1];
    for (int j = beg; j < end; ++j) {
        int s = col_idx[j];
        acc += g1[(long long)s * DIM + t];
    }
    float dv = dinv[d];
    float h = dv * acc + b1[t];
    h = fmaxf(h, 0.f);
    float z0 = h * W2[t * 2 + 0];
    float z1 = h * W2[t * 2 + 1];
#pragma unroll
    for (int off = 32; off > 0; off >>= 1) {
        z0 += __shfl_down(z0, off);
        z1 += __shfl_down(z1, off);
    }
    __shared__ float pz[2][2];
    int wid = t >> 6;
    if ((t & 63) == 0) { pz[wid][0] = z0; pz[wid][1] = z1; }
    __syncthreads();
    if (t == 0) {
        float s0 = pz[0][0] + pz[1][0];
        float s1 = pz[0][1] + pz[1][1];
        g2[d * 2 + 0] = dv * s0;
        g2[d * 2 + 1] = dv * s1;
    }
}

// One thread per dst node: aggregate g2 (2 floats), bias, log_softmax.
__global__ void agg2_kernel(const float* __restrict__ g2, const int* __restrict__ row_ptr,
                            const int* __restrict__ col_idx, const float* __restrict__ dinv,
                            const float* __restrict__ b2, float* __restrict__ out, int n) {
    int d = blockIdx.x * blockDim.x + threadIdx.x;
    if (d >= n) return;
    float a0 = g2[d * 2 + 0], a1 = g2[d * 2 + 1];
    int beg = row_ptr[d], end = row_ptr[d + 1];
    for (int j = beg; j < end; ++j) {
        int s = col_idx[j];
        a0 += g2[s * 2 + 0];
        a1 += g2[s * 2 + 1];
    }
    float dv = dinv[d];
    float z0 = dv * a0 + b2[0];
    float z1 = dv * a1 + b2[1];
    float m = fmaxf(z0, z1);
    float l = m + logf(expf(z0 - m) + expf(z1 - m));
    out[d * 2 + 0] = z0 - l;
    out[d * 2 + 1] = z1 - l;
}

extern "C" void kernel_launch(void* const* d_in, const int* in_sizes, int n_in,
                              void* d_out, int out_size, void* d_ws, size_t ws_size,
                              hipStream_t stream) {
    const float* x  = (const float*)d_in[0];
    const int*   ei = (const int*)d_in[1];
    const float* W1 = (const float*)d_in[2];
    const float* b1 = (const float*)d_in[3];
    const float* W2 = (const float*)d_in[4];
    const float* b2 = (const float*)d_in[5];
    float* out = (float*)d_out;

    int n = in_sizes[0] / DIM;   // 50000
    int e = in_sizes[1] / 2;     // 800000

    char* ws = (char*)d_ws;
    auto alloc = [&](size_t bytes) {
        char* p = ws;
        ws += (bytes + 255) & ~(size_t)255;
        return p;
    };
    int*   flag    = (int*)alloc(sizeof(int));
    int*   counts  = (int*)alloc((size_t)n * 4);
    int*   cursor  = (int*)alloc((size_t)n * 4);
    int*   row_ptr = (int*)alloc((size_t)(n + 1) * 4);
    float* dinv    = (float*)alloc((size_t)n * 4);
    int*   col_idx = (int*)alloc((size_t)e * 4);
    float* g1      = (float*)alloc((size_t)n * DIM * 4);
    float* g2      = (float*)alloc((size_t)n * 2 * 4);

    const int tb = 256;
    detect_kernel<<<1, 64, 0, stream>>>(ei, e, flag);
    init_counts<<<(n + tb - 1) / tb, tb, 0, stream>>>(counts, cursor, n);
    count_kernel<<<(e + tb - 1) / tb, tb, 0, stream>>>(ei, flag, counts, e);
    scan_kernel<<<1, 1024, 0, stream>>>(counts, row_ptr, n);
    dinv_kernel<<<(n + tb - 1) / tb, tb, 0, stream>>>(counts, dinv, n);
    fill_kernel<<<(e + tb - 1) / tb, tb, 0, stream>>>(ei, flag, row_ptr, cursor, col_idx, e);
    gemm1_kernel<<<(n + G1_ROWS - 1) / G1_ROWS, DIM, 0, stream>>>(x, W1, dinv, g1, n);
    agg1_kernel<<<n, DIM, 0, stream>>>(g1, row_ptr, col_idx, dinv, b1, W2, g2, n);
    agg2_kernel<<<(n + tb - 1) / tb, tb, 0, stream>>>(g2, row_ptr, col_idx, dinv, b2, out, n);
}

// Round 2
// 273.062 us; speedup vs baseline: 1.1329x; 1.1329x over previous
//
#include <hip/hip_runtime.h>
#include <hip/hip_fp16.h>

// ---------------------------------------------------------------------------
// GCN forward: 2-layer, fused normalization.
//   deg[d] = in_degree(d) + 1 (self loop);  dinv = 1/sqrt(deg)
//   g1 = fp16( dinv .* (x @ W1) )          [fp16 halves gather traffic]
//   h  = relu(dinv[d] * (sum_{s->d} g1[s] + g1[d]) + b1)
//   g2 = dinv .* (h @ W2)                  (fused into agg1 epilogue)
//   z  = dinv[d] * (sum_{s->d} g2[s] + g2[d]) + b2
//   out = log_softmax(z)
// ---------------------------------------------------------------------------

#define DIM 128

// edge_index may be int32 (JAX x64 disabled) or int64. Detect: int64 view has
// zero high words at odd int32 positions. Fused with counts/cursor init.
__global__ void init_detect_kernel(const int* __restrict__ ei,
                                   int* counts, int* cursor, int* flag, int n) {
    int i = blockIdx.x * blockDim.x + threadIdx.x;
    if (i < n) { counts[i] = 0; cursor[i] = 0; }
    if (i == 0) {
        int ok64 = 1;
        for (int k = 0; k < 32; ++k) {
            if (ei[2 * k + 1] != 0) { ok64 = 0; break; }
        }
        *flag = ok64;
    }
}

__device__ __forceinline__ int load_idx(const int* ei, long long pos, int is64) {
    if (is64) return (int)((const long long*)ei)[pos];
    return ei[pos];
}

__global__ void count_kernel(const int* __restrict__ ei, const int* __restrict__ flag,
                             int* counts, int e) {
    int i = blockIdx.x * blockDim.x + threadIdx.x;
    if (i >= e) return;
    int is64 = *flag;
    int d = load_idx(ei, (long long)e + i, is64);
    atomicAdd(&counts[d], 1);
}

// single-block exclusive scan over counts -> row_ptr (n up to ~50k)
__global__ void scan_kernel(const int* __restrict__ counts, int* __restrict__ row_ptr, int n) {
    __shared__ int lds[1024];
    int t = threadIdx.x;
    int chunk = (n + 1023) / 1024;
    int begin = t * chunk;
    int end = begin + chunk; if (end > n) end = n;
    int s = 0;
    for (int i = begin; i < end; ++i) s += counts[i];
    lds[t] = s;
    __syncthreads();
    for (int off = 1; off < 1024; off <<= 1) {
        int v = (t >= off) ? lds[t - off] : 0;
        __syncthreads();
        lds[t] += v;
        __syncthreads();
    }
    int excl = (t == 0) ? 0 : lds[t - 1];
    int run = excl;
    for (int i = begin; i < end; ++i) { row_ptr[i] = run; run += counts[i]; }
    if (end == n) row_ptr[n] = run;   // all tail threads write the same total
}

__global__ void dinv_kernel(const int* __restrict__ counts, float* __restrict__ dinv, int n) {
    int i = blockIdx.x * blockDim.x + threadIdx.x;
    if (i < n) dinv[i] = 1.0f / sqrtf((float)(counts[i] + 1));
}

__global__ void fill_kernel(const int* __restrict__ ei, const int* __restrict__ flag,
                            const int* __restrict__ row_ptr, int* cursor,
                            int* __restrict__ col_idx, int e) {
    int i = blockIdx.x * blockDim.x + threadIdx.x;
    if (i >= e) return;
    int is64 = *flag;
    int s = load_idx(ei, i, is64);
    int d = load_idx(ei, (long long)e + i, is64);
    int pos = row_ptr[d] + atomicAdd(&cursor[d], 1);
    col_idx[pos] = s;
}

// g1[row][c] = fp16( dinv[row] * sum_k x[row][k] * W1[k][c] )
// 128 threads (one per output column), 16 rows per block.
#define G1_ROWS 16
__global__ void gemm1_kernel(const float* __restrict__ x, const float* __restrict__ W1,
                             const float* __restrict__ dinv, __half* __restrict__ g1, int n) {
    __shared__ float4 xs[G1_ROWS][DIM / 4];
    int t = threadIdx.x;  // column 0..127
    int row0 = blockIdx.x * G1_ROWS;
    for (int r = 0; r < G1_ROWS; ++r) {
        int row = row0 + r;
        float v = 0.f, dv = 0.f;
        if (row < n) { v = x[(long long)row * DIM + t]; dv = dinv[row]; }
        ((float*)&xs[r][0])[t] = v * dv;
    }
    __syncthreads();
    float acc[G1_ROWS];
#pragma unroll
    for (int r = 0; r < G1_ROWS; ++r) acc[r] = 0.f;
    for (int k4 = 0; k4 < DIM / 4; ++k4) {
        float w0 = W1[(k4 * 4 + 0) * DIM + t];
        float w1 = W1[(k4 * 4 + 1) * DIM + t];
        float w2 = W1[(k4 * 4 + 2) * DIM + t];
        float w3 = W1[(k4 * 4 + 3) * DIM + t];
#pragma unroll
        for (int r = 0; r < G1_ROWS; ++r) {
            float4 xv = xs[r][k4];   // wave-uniform address -> broadcast
            acc[r] = fmaf(xv.x, w0, acc[r]);
            acc[r] = fmaf(xv.y, w1, acc[r]);
            acc[r] = fmaf(xv.z, w2, acc[r]);
            acc[r] = fmaf(xv.w, w3, acc[r]);
        }
    }
    for (int r = 0; r < G1_ROWS; ++r) {
        int row = row0 + r;
        if (row < n) g1[(long long)row * DIM + t] = __float2half(acc[r]);
    }
}

// One WAVE (64 lanes) per dst node, each lane owns 2 features (half2 = 4B).
// Per edge: 64 lanes x 4B = 256B coalesced gather. Cooperative index
// prefetch: lanes batch-load up to 64 col_idx, broadcast via shfl.
// Epilogue: relu + fused GEMM2 (128->2) reduced wave-locally by shuffle.
__global__ void agg1_kernel(const __half* __restrict__ g1, const int* __restrict__ row_ptr,
                            const int* __restrict__ col_idx, const float* __restrict__ dinv,
                            const float* __restrict__ b1, const float* __restrict__ W2,
                            float* __restrict__ g2, int n) {
    int lane = threadIdx.x & 63;
    int wid  = threadIdx.x >> 6;              // 0..3
    int d = blockIdx.x * 4 + wid;
    if (d >= n) return;
    const __half2* g1h = (const __half2*)g1;  // [n][64]
    float2 vf = __half22float2(g1h[(long long)d * 64 + lane]);  // self loop
    float acc0 = vf.x, acc1 = vf.y;
    int beg = row_ptr[d], end = row_ptr[d + 1];
    for (int j0 = beg; j0 < end; j0 += 64) {
        int cnt = end - j0; if (cnt > 64) cnt = 64;
        int idx = (j0 + lane < end) ? col_idx[j0 + lane] : 0;
#pragma unroll 4
        for (int i = 0; i < cnt; ++i) {
            int s = __shfl(idx, i);
            float2 uf = __half22float2(g1h[(long long)s * 64 + lane]);
            acc0 += uf.x; acc1 += uf.y;
        }
    }
    float dv = dinv[d];
    int f0 = lane * 2, f1 = f0 + 1;
    float h0 = fmaxf(dv * acc0 + b1[f0], 0.f);
    float h1 = fmaxf(dv * acc1 + b1[f1], 0.f);
    float z0 = fmaf(h1, W2[f1 * 2 + 0], h0 * W2[f0 * 2 + 0]);
    float z1 = fmaf(h1, W2[f1 * 2 + 1], h0 * W2[f0 * 2 + 1]);
#pragma unroll
    for (int off = 32; off > 0; off >>= 1) {
        z0 += __shfl_down(z0, off);
        z1 += __shfl_down(z1, off);
    }
    if (lane == 0) {
        g2[d * 2 + 0] = dv * z0;
        g2[d * 2 + 1] = dv * z1;
    }
}

// One thread per dst node: aggregate g2 (2 floats), bias, log_softmax.
__global__ void agg2_kernel(const float* __restrict__ g2, const int* __restrict__ row_ptr,
                            const int* __restrict__ col_idx, const float* __restrict__ dinv,
                            const float* __restrict__ b2, float* __restrict__ out, int n) {
    int d = blockIdx.x * blockDim.x + threadIdx.x;
    if (d >= n) return;
    float a0 = g2[d * 2 + 0], a1 = g2[d * 2 + 1];
    int beg = row_ptr[d], end = row_ptr[d + 1];
    for (int j = beg; j < end; ++j) {
        int s = col_idx[j];
        a0 += g2[s * 2 + 0];
        a1 += g2[s * 2 + 1];
    }
    float dv = dinv[d];
    float z0 = dv * a0 + b2[0];
    float z1 = dv * a1 + b2[1];
    float m = fmaxf(z0, z1);
    float l = m + logf(expf(z0 - m) + expf(z1 - m));
    out[d * 2 + 0] = z0 - l;
    out[d * 2 + 1] = z1 - l;
}

extern "C" void kernel_launch(void* const* d_in, const int* in_sizes, int n_in,
                              void* d_out, int out_size, void* d_ws, size_t ws_size,
                              hipStream_t stream) {
    const float* x  = (const float*)d_in[0];
    const int*   ei = (const int*)d_in[1];
    const float* W1 = (const float*)d_in[2];
    const float* b1 = (const float*)d_in[3];
    const float* W2 = (const float*)d_in[4];
    const float* b2 = (const float*)d_in[5];
    float* out = (float*)d_out;

    int n = in_sizes[0] / DIM;   // 50000
    int e = in_sizes[1] / 2;     // 800000

    char* ws = (char*)d_ws;
    auto alloc = [&](size_t bytes) {
        char* p = ws;
        ws += (bytes + 255) & ~(size_t)255;
        return p;
    };
    int*    flag    = (int*)alloc(sizeof(int));
    int*    counts  = (int*)alloc((size_t)n * 4);
    int*    cursor  = (int*)alloc((size_t)n * 4);
    int*    row_ptr = (int*)alloc((size_t)(n + 1) * 4);
    float*  dinv    = (float*)alloc((size_t)n * 4);
    int*    col_idx = (int*)alloc((size_t)e * 4);
    __half* g1      = (__half*)alloc((size_t)n * DIM * 2);
    float*  g2      = (float*)alloc((size_t)n * 2 * 4);

    const int tb = 256;
    init_detect_kernel<<<(n + tb - 1) / tb, tb, 0, stream>>>(ei, counts, cursor, flag, n);
    count_kernel<<<(e + tb - 1) / tb, tb, 0, stream>>>(ei, flag, counts, e);
    scan_kernel<<<1, 1024, 0, stream>>>(counts, row_ptr, n);
    dinv_kernel<<<(n + tb - 1) / tb, tb, 0, stream>>>(counts, dinv, n);
    fill_kernel<<<(e + tb - 1) / tb, tb, 0, stream>>>(ei, flag, row_ptr, cursor, col_idx, e);
    gemm1_kernel<<<(n + G1_ROWS - 1) / G1_ROWS, DIM, 0, stream>>>(x, W1, dinv, g1, n);
    agg1_kernel<<<(n + 3) / 4, 256, 0, stream>>>(g1, row_ptr, col_idx, dinv, b1, W2, g2, n);
    agg2_kernel<<<(n + tb - 1) / tb, tb, 0, stream>>>(g2, row_ptr, col_idx, dinv, b2, out, n);
}

// Round 3
// 203.718 us; speedup vs baseline: 1.5185x; 1.3404x over previous
//
#include <hip/hip_runtime.h>
#include <hip/hip_fp16.h>

// ---------------------------------------------------------------------------
// GCN forward: 2-layer, fused normalization.
//   deg[d] = in_degree(d) + 1 (self loop);  dinv = 1/sqrt(deg)
//   g1 = fp16( dinv .* (x @ W1) )          [fp16 halves gather traffic]
//   h  = relu(dinv[d] * (sum_{s->d} g1[s] + g1[d]) + b1)
//   g2 = dinv .* (h @ W2)                  (fused into agg1 epilogue)
//   z  = dinv[d] * (sum_{s->d} g2[s] + g2[d]) + b2
//   out = log_softmax(z)
// CSR row_ptr via 3-phase hierarchical scan (single-block scan was 76us:
// one block on 256 CUs = pure latency serialization).
// ---------------------------------------------------------------------------

#define DIM 128
#define SCAN_TILE 256

// edge_index may be int32 (JAX x64 disabled) or int64. Detect: int64 view has
// zero high words at odd int32 positions. Fused with counts/cursor init.
__global__ void init_detect_kernel(const int* __restrict__ ei,
                                   int* counts, int* cursor, int* flag, int n) {
    int i = blockIdx.x * blockDim.x + threadIdx.x;
    if (i < n) { counts[i] = 0; cursor[i] = 0; }
    if (i == 0) {
        int ok64 = 1;
        for (int k = 0; k < 32; ++k) {
            if (ei[2 * k + 1] != 0) { ok64 = 0; break; }
        }
        *flag = ok64;
    }
}

__device__ __forceinline__ int load_idx(const int* ei, long long pos, int is64) {
    if (is64) return (int)((const long long*)ei)[pos];
    return ei[pos];
}

__global__ void count_kernel(const int* __restrict__ ei, const int* __restrict__ flag,
                             int* counts, int e) {
    int i = blockIdx.x * blockDim.x + threadIdx.x;
    if (i >= e) return;
    int is64 = *flag;
    int d = load_idx(ei, (long long)e + i, is64);
    atomicAdd(&counts[d], 1);
}

// ---- hierarchical scan: A) tile sums, B) scan tile sums, C) tile scan + dinv
__global__ void scanA_kernel(const int* __restrict__ counts, int* __restrict__ tileSums, int n) {
    int t = threadIdx.x;
    int i = blockIdx.x * SCAN_TILE + t;
    int v = (i < n) ? counts[i] : 0;
    int lane = t & 63;
#pragma unroll
    for (int off = 32; off > 0; off >>= 1) v += __shfl_down(v, off);
    __shared__ int ws[4];
    if (lane == 0) ws[t >> 6] = v;
    __syncthreads();
    if (t == 0) tileSums[blockIdx.x] = ws[0] + ws[1] + ws[2] + ws[3];
}

// single block, ntiles <= 256: exclusive scan in place, total at [ntiles]
__global__ void scanB_kernel(int* tileSums, int ntiles) {
    int t = threadIdx.x;
    int v = (t < ntiles) ? tileSums[t] : 0;
    int lane = t & 63, w = t >> 6;
    int x = v;
#pragma unroll
    for (int off = 1; off < 64; off <<= 1) {
        int y = __shfl_up(x, off);
        if (lane >= off) x += y;
    }
    __shared__ int ws[4];
    if (lane == 63) ws[w] = x;
    __syncthreads();
    int add = 0;
    for (int k = 0; k < w; ++k) add += ws[k];
    int incl = x + add;
    if (t < ntiles) tileSums[t] = incl - v;          // exclusive
    if (t == ntiles - 1) tileSums[ntiles] = incl;    // grand total
}

__global__ void scanC_kernel(const int* __restrict__ counts, const int* __restrict__ tileOff,
                             int* __restrict__ row_ptr, float* __restrict__ dinv, int n) {
    int t = threadIdx.x;
    int i = blockIdx.x * SCAN_TILE + t;
    int v = (i < n) ? counts[i] : 0;
    int lane = t & 63, w = t >> 6;
    int x = v;
#pragma unroll
    for (int off = 1; off < 64; off <<= 1) {
        int y = __shfl_up(x, off);
        if (lane >= off) x += y;
    }
    __shared__ int ws[4];
    if (lane == 63) ws[w] = x;
    __syncthreads();
    int add = tileOff[blockIdx.x];
    for (int k = 0; k < w; ++k) add += ws[k];
    if (i < n) {
        row_ptr[i] = add + x - v;
        dinv[i] = rsqrtf((float)(v + 1));
    }
    if (i == n - 1) row_ptr[n] = add + x;            // total edge count
}

__global__ void fill_kernel(const int* __restrict__ ei, const int* __restrict__ flag,
                            const int* __restrict__ row_ptr, int* cursor,
                            int* __restrict__ col_idx, int e) {
    int i = blockIdx.x * blockDim.x + threadIdx.x;
    if (i >= e) return;
    int is64 = *flag;
    int s = load_idx(ei, i, is64);
    int d = load_idx(ei, (long long)e + i, is64);
    int pos = row_ptr[d] + atomicAdd(&cursor[d], 1);
    col_idx[pos] = s;
}

// g1[row][c] = fp16( dinv[row] * sum_k x[row][k] * W1[k][c] )
// 128 threads (one per output column), 16 rows per block.
#define G1_ROWS 16
__global__ void gemm1_kernel(const float* __restrict__ x, const float* __restrict__ W1,
                             const float* __restrict__ dinv, __half* __restrict__ g1, int n) {
    __shared__ float4 xs[G1_ROWS][DIM / 4];
    int t = threadIdx.x;  // column 0..127
    int row0 = blockIdx.x * G1_ROWS;
    for (int r = 0; r < G1_ROWS; ++r) {
        int row = row0 + r;
        float v = 0.f, dv = 0.f;
        if (row < n) { v = x[(long long)row * DIM + t]; dv = dinv[row]; }
        ((float*)&xs[r][0])[t] = v * dv;
    }
    __syncthreads();
    float acc[G1_ROWS];
#pragma unroll
    for (int r = 0; r < G1_ROWS; ++r) acc[r] = 0.f;
    for (int k4 = 0; k4 < DIM / 4; ++k4) {
        float w0 = W1[(k4 * 4 + 0) * DIM + t];
        float w1 = W1[(k4 * 4 + 1) * DIM + t];
        float w2 = W1[(k4 * 4 + 2) * DIM + t];
        float w3 = W1[(k4 * 4 + 3) * DIM + t];
#pragma unroll
        for (int r = 0; r < G1_ROWS; ++r) {
            float4 xv = xs[r][k4];   // wave-uniform address -> broadcast
            acc[r] = fmaf(xv.x, w0, acc[r]);
            acc[r] = fmaf(xv.y, w1, acc[r]);
            acc[r] = fmaf(xv.z, w2, acc[r]);
            acc[r] = fmaf(xv.w, w3, acc[r]);
        }
    }
    for (int r = 0; r < G1_ROWS; ++r) {
        int row = row0 + r;
        if (row < n) g1[(long long)row * DIM + t] = __float2half(acc[r]);
    }
}

// One WAVE (64 lanes) per dst node, each lane owns 2 features (half2 = 4B).
// Per edge: 64 lanes x 4B = 256B coalesced gather. Cooperative index
// prefetch: lanes batch-load up to 64 col_idx, broadcast via shfl.
// Epilogue: relu + fused GEMM2 (128->2) reduced wave-locally by shuffle.
__global__ void agg1_kernel(const __half* __restrict__ g1, const int* __restrict__ row_ptr,
                            const int* __restrict__ col_idx, const float* __restrict__ dinv,
                            const float* __restrict__ b1, const float* __restrict__ W2,
                            float* __restrict__ g2, int n) {
    int lane = threadIdx.x & 63;
    int wid  = threadIdx.x >> 6;              // 0..3
    int d = blockIdx.x * 4 + wid;
    if (d >= n) return;
    const __half2* g1h = (const __half2*)g1;  // [n][64]
    float2 vf = __half22float2(g1h[(long long)d * 64 + lane]);  // self loop
    float acc0 = vf.x, acc1 = vf.y;
    int beg = row_ptr[d], end = row_ptr[d + 1];
    for (int j0 = beg; j0 < end; j0 += 64) {
        int cnt = end - j0; if (cnt > 64) cnt = 64;
        int idx = (j0 + lane < end) ? col_idx[j0 + lane] : 0;
#pragma unroll 4
        for (int i = 0; i < cnt; ++i) {
            int s = __shfl(idx, i);
            float2 uf = __half22float2(g1h[(long long)s * 64 + lane]);
            acc0 += uf.x; acc1 += uf.y;
        }
    }
    float dv = dinv[d];
    int f0 = lane * 2, f1 = f0 + 1;
    float h0 = fmaxf(dv * acc0 + b1[f0], 0.f);
    float h1 = fmaxf(dv * acc1 + b1[f1], 0.f);
    float z0 = fmaf(h1, W2[f1 * 2 + 0], h0 * W2[f0 * 2 + 0]);
    float z1 = fmaf(h1, W2[f1 * 2 + 1], h0 * W2[f0 * 2 + 1]);
#pragma unroll
    for (int off = 32; off > 0; off >>= 1) {
        z0 += __shfl_down(z0, off);
        z1 += __shfl_down(z1, off);
    }
    if (lane == 0) {
        g2[d * 2 + 0] = dv * z0;
        g2[d * 2 + 1] = dv * z1;
    }
}

// One thread per dst node: aggregate g2 (2 floats), bias, log_softmax.
__global__ void agg2_kernel(const float* __restrict__ g2, const int* __restrict__ row_ptr,
                            const int* __restrict__ col_idx, const float* __restrict__ dinv,
                            const float* __restrict__ b2, float* __restrict__ out, int n) {
    int d = blockIdx.x * blockDim.x + threadIdx.x;
    if (d >= n) return;
    float a0 = g2[d * 2 + 0], a1 = g2[d * 2 + 1];
    int beg = row_ptr[d], end = row_ptr[d + 1];
    for (int j = beg; j < end; ++j) {
        int s = col_idx[j];
        a0 += g2[s * 2 + 0];
        a1 += g2[s * 2 + 1];
    }
    float dv = dinv[d];
    float z0 = dv * a0 + b2[0];
    float z1 = dv * a1 + b2[1];
    float m = fmaxf(z0, z1);
    float l = m + logf(expf(z0 - m) + expf(z1 - m));
    out[d * 2 + 0] = z0 - l;
    out[d * 2 + 1] = z1 - l;
}

extern "C" void kernel_launch(void* const* d_in, const int* in_sizes, int n_in,
                              void* d_out, int out_size, void* d_ws, size_t ws_size,
                              hipStream_t stream) {
    const float* x  = (const float*)d_in[0];
    const int*   ei = (const int*)d_in[1];
    const float* W1 = (const float*)d_in[2];
    const float* b1 = (const float*)d_in[3];
    const float* W2 = (const float*)d_in[4];
    const float* b2 = (const float*)d_in[5];
    float* out = (float*)d_out;

    int n = in_sizes[0] / DIM;   // 50000
    int e = in_sizes[1] / 2;     // 800000
    int ntiles = (n + SCAN_TILE - 1) / SCAN_TILE;   // 196

    char* ws = (char*)d_ws;
    auto alloc = [&](size_t bytes) {
        char* p = ws;
        ws += (bytes + 255) & ~(size_t)255;
        return p;
    };
    int*    flag     = (int*)alloc(sizeof(int));
    int*    counts   = (int*)alloc((size_t)n * 4);
    int*    cursor   = (int*)alloc((size_t)n * 4);
    int*    row_ptr  = (int*)alloc((size_t)(n + 1) * 4);
    int*    tileSums = (int*)alloc((size_t)(ntiles + 1) * 4);
    float*  dinv     = (float*)alloc((size_t)n * 4);
    int*    col_idx  = (int*)alloc((size_t)e * 4);
    __half* g1       = (__half*)alloc((size_t)n * DIM * 2);
    float*  g2       = (float*)alloc((size_t)n * 2 * 4);

    const int tb = 256;
    init_detect_kernel<<<(n + tb - 1) / tb, tb, 0, stream>>>(ei, counts, cursor, flag, n);
    count_kernel<<<(e + tb - 1) / tb, tb, 0, stream>>>(ei, flag, counts, e);
    scanA_kernel<<<ntiles, SCAN_TILE, 0, stream>>>(counts, tileSums, n);
    scanB_kernel<<<1, 256, 0, stream>>>(tileSums, ntiles);
    scanC_kernel<<<ntiles, SCAN_TILE, 0, stream>>>(counts, tileSums, row_ptr, dinv, n);
    fill_kernel<<<(e + tb - 1) / tb, tb, 0, stream>>>(ei, flag, row_ptr, cursor, col_idx, e);
    gemm1_kernel<<<(n + G1_ROWS - 1) / G1_ROWS, DIM, 0, stream>>>(x, W1, dinv, g1, n);
    agg1_kernel<<<(n + 3) / 4, 256, 0, stream>>>(g1, row_ptr, col_idx, dinv, b1, W2, g2, n);
    agg2_kernel<<<(n + tb - 1) / tb, tb, 0, stream>>>(g2, row_ptr, col_idx, dinv, b2, out, n);
}

// Round 4
// 178.028 us; speedup vs baseline: 1.7376x; 1.1443x over previous
//
#include <hip/hip_runtime.h>
#include <hip/hip_fp16.h>

// ---------------------------------------------------------------------------
// GCN forward: 2-layer, fused normalization.
//   deg[d] = in_degree(d) + 1 (self loop);  dinv = 1/sqrt(deg)
//   g1 = fp16( (x @ W1) .* dinv )          [fp16 halves gather traffic]
//   h  = relu(dinv[d] * (sum_{s->d} g1[s] + g1[d]) + b1)
//   g2 = dinv .* (h @ W2)                  (fused into agg1 epilogue)
//   z  = dinv[d] * (sum_{s->d} g2[s] + g2[d]) + b2
//   out = log_softmax(z)
// Techniques: wave-uniform index reads scalarized (s_load, no shfl);
// scalar-pipe x loads in gemm1 (VALU issues only FMA); ticket-based CSR fill
// (no atomics in fill); wave-parallel layer-2 aggregation.
// ---------------------------------------------------------------------------

#define DIM 128
#define SCAN_TILE 256

// edge_index may be int32 (JAX x64 disabled) or int64. Detect: int64 view has
// zero high words at odd int32 positions. Fused with counts/cursor init.
__global__ void init_detect_kernel(const int* __restrict__ ei,
                                   int* counts, int* cursor, int* flag, int n) {
    int i = blockIdx.x * blockDim.x + threadIdx.x;
    if (i < n) { counts[i] = 0; cursor[i] = 0; }
    if (i == 0) {
        int ok64 = 1;
        for (int k = 0; k < 32; ++k) {
            if (ei[2 * k + 1] != 0) { ok64 = 0; break; }
        }
        *flag = ok64;
    }
}

__device__ __forceinline__ int load_idx(const int* ei, long long pos, int is64) {
    if (is64) return (int)((const long long*)ei)[pos];
    return ei[pos];
}

// Decode edges once, count in-degree, and hand out a ticket (slot within the
// dst row) so the fill pass needs no atomics.
__global__ void count_ticket_kernel(const int* __restrict__ ei, const int* __restrict__ flag,
                                    int* counts, int* __restrict__ s32, int* __restrict__ d32,
                                    int* __restrict__ ticket, int e) {
    int i = blockIdx.x * blockDim.x + threadIdx.x;
    if (i >= e) return;
    int is64 = *flag;
    int s = load_idx(ei, i, is64);
    int d = load_idx(ei, (long long)e + i, is64);
    s32[i] = s;
    d32[i] = d;
    ticket[i] = atomicAdd(&counts[d], 1);
}

__global__ void fill_ticket_kernel(const int* __restrict__ s32, const int* __restrict__ d32,
                                   const int* __restrict__ ticket, const int* __restrict__ row_ptr,
                                   int* __restrict__ col_idx, int e) {
    int i = blockIdx.x * blockDim.x + threadIdx.x;
    if (i >= e) return;
    int d = d32[i];
    col_idx[row_ptr[d] + ticket[i]] = s32[i];
}

// Fallback path (small workspace): atomic cursor fill.
__global__ void count_kernel(const int* __restrict__ ei, const int* __restrict__ flag,
                             int* counts, int e) {
    int i = blockIdx.x * blockDim.x + threadIdx.x;
    if (i >= e) return;
    int is64 = *flag;
    int d = load_idx(ei, (long long)e + i, is64);
    atomicAdd(&counts[d], 1);
}

__global__ void fill_kernel(const int* __restrict__ ei, const int* __restrict__ flag,
                            const int* __restrict__ row_ptr, int* cursor,
                            int* __restrict__ col_idx, int e) {
    int i = blockIdx.x * blockDim.x + threadIdx.x;
    if (i >= e) return;
    int is64 = *flag;
    int s = load_idx(ei, i, is64);
    int d = load_idx(ei, (long long)e + i, is64);
    int pos = row_ptr[d] + atomicAdd(&cursor[d], 1);
    col_idx[pos] = s;
}

// ---- hierarchical scan: A) tile sums, B) scan tile sums, C) tile scan + dinv
__global__ void scanA_kernel(const int* __restrict__ counts, int* __restrict__ tileSums, int n) {
    int t = threadIdx.x;
    int i = blockIdx.x * SCAN_TILE + t;
    int v = (i < n) ? counts[i] : 0;
    int lane = t & 63;
#pragma unroll
    for (int off = 32; off > 0; off >>= 1) v += __shfl_down(v, off);
    __shared__ int ws[4];
    if (lane == 0) ws[t >> 6] = v;
    __syncthreads();
    if (t == 0) tileSums[blockIdx.x] = ws[0] + ws[1] + ws[2] + ws[3];
}

// single block, ntiles <= 256: exclusive scan in place, total at [ntiles]
__global__ void scanB_kernel(int* tileSums, int ntiles) {
    int t = threadIdx.x;
    int v = (t < ntiles) ? tileSums[t] : 0;
    int lane = t & 63, w = t >> 6;
    int x = v;
#pragma unroll
    for (int off = 1; off < 64; off <<= 1) {
        int y = __shfl_up(x, off);
        if (lane >= off) x += y;
    }
    __shared__ int ws[4];
    if (lane == 63) ws[w] = x;
    __syncthreads();
    int add = 0;
    for (int k = 0; k < w; ++k) add += ws[k];
    int incl = x + add;
    if (t < ntiles) tileSums[t] = incl - v;          // exclusive
    if (t == ntiles - 1) tileSums[ntiles] = incl;    // grand total
}

__global__ void scanC_kernel(const int* __restrict__ counts, const int* __restrict__ tileOff,
                             int* __restrict__ row_ptr, float* __restrict__ dinv, int n) {
    int t = threadIdx.x;
    int i = blockIdx.x * SCAN_TILE + t;
    int v = (i < n) ? counts[i] : 0;
    int lane = t & 63, w = t >> 6;
    int x = v;
#pragma unroll
    for (int off = 1; off < 64; off <<= 1) {
        int y = __shfl_up(x, off);
        if (lane >= off) x += y;
    }
    __shared__ int ws[4];
    if (lane == 63) ws[w] = x;
    __syncthreads();
    int add = tileOff[blockIdx.x];
    for (int k = 0; k < w; ++k) add += ws[k];
    if (i < n) {
        row_ptr[i] = add + x - v;
        dinv[i] = rsqrtf((float)(v + 1));
    }
    if (i == n - 1) row_ptr[n] = add + x;            // total edge count
}

// g1[row][c] = fp16( dinv[row] * (x @ W1)[row][c] )
// 128 threads (one per output column), 16 rows per block. x-tile addresses are
// thread-independent -> compiler emits scalar (SMEM-pipe) loads; VALU issues
// only FMAs. No LDS.
#define G1_ROWS 16
__global__ void gemm1_kernel(const float* __restrict__ x, const float* __restrict__ W1,
                             const float* __restrict__ dinv, __half* __restrict__ g1, int n) {
    int t = threadIdx.x;                 // column 0..127
    int row0 = blockIdx.x * G1_ROWS;
    int full = (row0 + G1_ROWS <= n);
    const float* xr = x + (size_t)row0 * DIM;
    float acc[G1_ROWS];
#pragma unroll
    for (int r = 0; r < G1_ROWS; ++r) acc[r] = 0.f;
    if (full) {
        for (int k4 = 0; k4 < DIM / 4; ++k4) {
            float4 xv[G1_ROWS];
#pragma unroll
            for (int r = 0; r < G1_ROWS; ++r)
                xv[r] = *(const float4*)(xr + r * DIM + k4 * 4);   // uniform -> s_load
            float w0 = W1[(k4 * 4 + 0) * DIM + t];
            float w1 = W1[(k4 * 4 + 1) * DIM + t];
            float w2 = W1[(k4 * 4 + 2) * DIM + t];
            float w3 = W1[(k4 * 4 + 3) * DIM + t];
#pragma unroll
            for (int r = 0; r < G1_ROWS; ++r) {
                acc[r] = fmaf(xv[r].x, w0, acc[r]);
                acc[r] = fmaf(xv[r].y, w1, acc[r]);
                acc[r] = fmaf(xv[r].z, w2, acc[r]);
                acc[r] = fmaf(xv[r].w, w3, acc[r]);
            }
        }
#pragma unroll
        for (int r = 0; r < G1_ROWS; ++r) {
            int row = row0 + r;
            g1[(size_t)row * DIM + t] = __float2half(acc[r] * dinv[row]);
        }
    } else {
        int nr = n - row0; if (nr < 0) nr = 0;
        for (int k4 = 0; k4 < DIM / 4; ++k4) {
            float w0 = W1[(k4 * 4 + 0) * DIM + t];
            float w1 = W1[(k4 * 4 + 1) * DIM + t];
            float w2 = W1[(k4 * 4 + 2) * DIM + t];
            float w3 = W1[(k4 * 4 + 3) * DIM + t];
            for (int r = 0; r < nr; ++r) {
                float4 xv = *(const float4*)(xr + r * DIM + k4 * 4);
                acc[r] = fmaf(xv.x, w0, acc[r]);
                acc[r] = fmaf(xv.y, w1, acc[r]);
                acc[r] = fmaf(xv.z, w2, acc[r]);
                acc[r] = fmaf(xv.w, w3, acc[r]);
            }
        }
        for (int r = 0; r < nr; ++r) {
            int row = row0 + r;
            g1[(size_t)row * DIM + t] = __float2half(acc[r] * dinv[row]);
        }
    }
}

// One WAVE per dst node, lane owns 2 features (half2 = 4B; 256B/edge wave-wide).
// row_ptr/col_idx reads are wave-uniform -> scalarized (s_load), no shfl
// broadcast. 8 edges in flight per iteration, pairwise sums.
__global__ void agg1_kernel(const __half* __restrict__ g1, const int* __restrict__ row_ptr,
                            const int* __restrict__ col_idx, const float* __restrict__ dinv,
                            const float* __restrict__ b1, const float* __restrict__ W2,
                            float* __restrict__ g2, int n) {
    int lane = threadIdx.x & 63;
    int wid  = threadIdx.x >> 6;              // 0..3
    int d = blockIdx.x * 4 + wid;
    if (d >= n) return;
    const __half2* base = (const __half2*)g1 + lane;   // [n][64] half2
    float2 vf = __half22float2(base[d * 64]);          // self loop
    float acc0 = vf.x, acc1 = vf.y;
    int beg = __builtin_amdgcn_readfirstlane(row_ptr[d]);
    int end = __builtin_amdgcn_readfirstlane(row_ptr[d + 1]);
    int j = beg;
    for (; j + 8 <= end; j += 8) {
        int s0 = col_idx[j + 0], s1 = col_idx[j + 1];
        int s2 = col_idx[j + 2], s3 = col_idx[j + 3];
        int s4 = col_idx[j + 4], s5 = col_idx[j + 5];
        int s6 = col_idx[j + 6], s7 = col_idx[j + 7];
        __half2 h0 = base[s0 * 64], h1 = base[s1 * 64];
        __half2 h2 = base[s2 * 64], h3 = base[s3 * 64];
        __half2 h4 = base[s4 * 64], h5 = base[s5 * 64];
        __half2 h6 = base[s6 * 64], h7 = base[s7 * 64];
        float2 u0 = __half22float2(h0), u1 = __half22float2(h1);
        float2 u2 = __half22float2(h2), u3 = __half22float2(h3);
        float2 u4 = __half22float2(h4), u5 = __half22float2(h5);
        float2 u6 = __half22float2(h6), u7 = __half22float2(h7);
        acc0 += ((u0.x + u1.x) + (u2.x + u3.x)) + ((u4.x + u5.x) + (u6.x + u7.x));
        acc1 += ((u0.y + u1.y) + (u2.y + u3.y)) + ((u4.y + u5.y) + (u6.y + u7.y));
    }
    for (; j < end; ++j) {
        float2 u = __half22float2(base[col_idx[j] * 64]);
        acc0 += u.x; acc1 += u.y;
    }
    float dv = dinv[d];
    int f0 = lane * 2, f1 = f0 + 1;
    float h0 = fmaxf(dv * acc0 + b1[f0], 0.f);
    float h1 = fmaxf(dv * acc1 + b1[f1], 0.f);
    float z0 = fmaf(h1, W2[f1 * 2 + 0], h0 * W2[f0 * 2 + 0]);
    float z1 = fmaf(h1, W2[f1 * 2 + 1], h0 * W2[f0 * 2 + 1]);
#pragma unroll
    for (int off = 32; off > 0; off >>= 1) {
        z0 += __shfl_down(z0, off);
        z1 += __shfl_down(z1, off);
    }
    if (lane == 0) {
        g2[d * 2 + 0] = dv * z0;
        g2[d * 2 + 1] = dv * z1;
    }
}

// One WAVE per dst node, lane per edge (parallel gather), shuffle reduce,
// then bias + log_softmax on lane 0.
__global__ void agg2_kernel(const float* __restrict__ g2, const int* __restrict__ row_ptr,
                            const int* __restrict__ col_idx, const float* __restrict__ dinv,
                            const float* __restrict__ b2, float* __restrict__ out, int n) {
    int lane = threadIdx.x & 63;
    int wid  = threadIdx.x >> 6;
    int d = blockIdx.x * 4 + wid;
    if (d >= n) return;
    int beg = __builtin_amdgcn_readfirstlane(row_ptr[d]);
    int end = __builtin_amdgcn_readfirstlane(row_ptr[d + 1]);
    float a0 = 0.f, a1 = 0.f;
    const float2* g2v = (const float2*)g2;
    for (int j0 = beg; j0 < end; j0 += 64) {
        int j = j0 + lane;
        if (j < end) {
            float2 v = g2v[col_idx[j]];
            a0 += v.x; a1 += v.y;
        }
    }
#pragma unroll
    for (int off = 32; off > 0; off >>= 1) {
        a0 += __shfl_down(a0, off);
        a1 += __shfl_down(a1, off);
    }
    if (lane == 0) {
        float2 self = g2v[d];
        float dv = dinv[d];
        float z0 = dv * (a0 + self.x) + b2[0];
        float z1 = dv * (a1 + self.y) + b2[1];
        float m = fmaxf(z0, z1);
        float l = m + logf(expf(z0 - m) + expf(z1 - m));
        out[d * 2 + 0] = z0 - l;
        out[d * 2 + 1] = z1 - l;
    }
}

extern "C" void kernel_launch(void* const* d_in, const int* in_sizes, int n_in,
                              void* d_out, int out_size, void* d_ws, size_t ws_size,
                              hipStream_t stream) {
    const float* x  = (const float*)d_in[0];
    const int*   ei = (const int*)d_in[1];
    const float* W1 = (const float*)d_in[2];
    const float* b1 = (const float*)d_in[3];
    const float* W2 = (const float*)d_in[4];
    const float* b2 = (const float*)d_in[5];
    float* out = (float*)d_out;

    int n = in_sizes[0] / DIM;   // 50000
    int e = in_sizes[1] / 2;     // 800000
    int ntiles = (n + SCAN_TILE - 1) / SCAN_TILE;   // 196

    char* wsp = (char*)d_ws;
    size_t used = 0;
    auto alloc = [&](size_t bytes) {
        char* p = wsp + used;
        used += (bytes + 255) & ~(size_t)255;
        return p;
    };
    int*    flag     = (int*)alloc(sizeof(int));
    int*    counts   = (int*)alloc((size_t)n * 4);
    int*    cursor   = (int*)alloc((size_t)n * 4);
    int*    row_ptr  = (int*)alloc((size_t)(n + 1) * 4);
    int*    tileSums = (int*)alloc((size_t)(ntiles + 1) * 4);
    float*  dinv     = (float*)alloc((size_t)n * 4);
    int*    col_idx  = (int*)alloc((size_t)e * 4);
    __half* g1       = (__half*)alloc((size_t)n * DIM * 2);
    float*  g2       = (float*)alloc((size_t)n * 2 * 4);

    size_t per_e = ((size_t)e * 4 + 255) & ~(size_t)255;
    bool ticket_path = (used + 3 * per_e <= ws_size);
    int *s32 = nullptr, *d32 = nullptr, *ticket = nullptr;
    if (ticket_path) {
        s32    = (int*)alloc((size_t)e * 4);
        d32    = (int*)alloc((size_t)e * 4);
        ticket = (int*)alloc((size_t)e * 4);
    }

    const int tb = 256;
    int eblk = (e + tb - 1) / tb;
    init_detect_kernel<<<(n + tb - 1) / tb, tb, 0, stream>>>(ei, counts, cursor, flag, n);
    if (ticket_path)
        count_ticket_kernel<<<eblk, tb, 0, stream>>>(ei, flag, counts, s32, d32, ticket, e);
    else
        count_kernel<<<eblk, tb, 0, stream>>>(ei, flag, counts, e);
    scanA_kernel<<<ntiles, SCAN_TILE, 0, stream>>>(counts, tileSums, n);
    scanB_kernel<<<1, 256, 0, stream>>>(tileSums, ntiles);
    scanC_kernel<<<ntiles, SCAN_TILE, 0, stream>>>(counts, tileSums, row_ptr, dinv, n);
    if (ticket_path)
        fill_ticket_kernel<<<eblk, tb, 0, stream>>>(s32, d32, ticket, row_ptr, col_idx, e);
    else
        fill_kernel<<<eblk, tb, 0, stream>>>(ei, flag, row_ptr, cursor, col_idx, e);
    gemm1_kernel<<<(n + G1_ROWS - 1) / G1_ROWS, DIM, 0, stream>>>(x, W1, dinv, g1, n);
    agg1_kernel<<<(n + 3) / 4, 256, 0, stream>>>(g1, row_ptr, col_idx, dinv, b1, W2, g2, n);
    agg2_kernel<<<(n + 3) / 4, 256, 0, stream>>>(g2, row_ptr, col_idx, dinv, b2, out, n);
}

// Round 6
// 144.965 us; speedup vs baseline: 2.1340x; 1.2281x over previous
//
#include <hip/hip_runtime.h>
#include <hip/hip_fp16.h>

// ---------------------------------------------------------------------------
// GCN forward: 2-layer, fused normalization.
//   deg[d] = in_degree(d) + 1 (self loop);  dinv = 1/sqrt(deg)
//   g1 = fp16( (x @ W1) .* dinv )          [fp16 halves gather traffic]
//   h  = relu(dinv[d] * (sum_{s->d} g1[s] + g1[d]) + b1)
//   g2 = dinv .* (h @ W2)                  (fused into agg1 epilogue)
//   z  = dinv[d] * (sum_{s->d} g2[s] + g2[d]) + b2
//   out = log_softmax(z)
// gemm1: register-tiled VALU GEMM (4x8 acc/thread, LDS-staged x + W panels).
// Round-5 bug: x-tile read dropped the p*32 panel offset (read k 0..31 for
// every panel) -> fixed here.
// ---------------------------------------------------------------------------

#define DIM 128
#define SCAN_TILE 256

// edge_index may be int32 (JAX x64 disabled) or int64. Detect: int64 view has
// zero high words at odd int32 positions. Fused with counts/cursor init.
__global__ void init_detect_kernel(const int* __restrict__ ei,
                                   int* counts, int* cursor, int* flag, int n) {
    int i = blockIdx.x * blockDim.x + threadIdx.x;
    if (i < n) { counts[i] = 0; cursor[i] = 0; }
    if (i == 0) {
        int ok64 = 1;
        for (int k = 0; k < 32; ++k) {
            if (ei[2 * k + 1] != 0) { ok64 = 0; break; }
        }
        *flag = ok64;
    }
}

__device__ __forceinline__ int load_idx(const int* ei, long long pos, int is64) {
    if (is64) return (int)((const long long*)ei)[pos];
    return ei[pos];
}

// Decode edges once, count in-degree, and hand out a ticket (slot within the
// dst row) so the fill pass needs no atomics.
__global__ void count_ticket_kernel(const int* __restrict__ ei, const int* __restrict__ flag,
                                    int* counts, int* __restrict__ s32, int* __restrict__ d32,
                                    int* __restrict__ ticket, int e) {
    int i = blockIdx.x * blockDim.x + threadIdx.x;
    if (i >= e) return;
    int is64 = *flag;
    int s = load_idx(ei, i, is64);
    int d = load_idx(ei, (long long)e + i, is64);
    s32[i] = s;
    d32[i] = d;
    ticket[i] = atomicAdd(&counts[d], 1);
}

__global__ void fill_ticket_kernel(const int* __restrict__ s32, const int* __restrict__ d32,
                                   const int* __restrict__ ticket, const int* __restrict__ row_ptr,
                                   int* __restrict__ col_idx, int e) {
    int i = blockIdx.x * blockDim.x + threadIdx.x;
    if (i >= e) return;
    int d = d32[i];
    col_idx[row_ptr[d] + ticket[i]] = s32[i];
}

// Fallback path (small workspace): atomic cursor fill.
__global__ void count_kernel(const int* __restrict__ ei, const int* __restrict__ flag,
                             int* counts, int e) {
    int i = blockIdx.x * blockDim.x + threadIdx.x;
    if (i >= e) return;
    int is64 = *flag;
    int d = load_idx(ei, (long long)e + i, is64);
    atomicAdd(&counts[d], 1);
}

__global__ void fill_kernel(const int* __restrict__ ei, const int* __restrict__ flag,
                            const int* __restrict__ row_ptr, int* cursor,
                            int* __restrict__ col_idx, int e) {
    int i = blockIdx.x * blockDim.x + threadIdx.x;
    if (i >= e) return;
    int is64 = *flag;
    int s = load_idx(ei, i, is64);
    int d = load_idx(ei, (long long)e + i, is64);
    int pos = row_ptr[d] + atomicAdd(&cursor[d], 1);
    col_idx[pos] = s;
}

// ---- hierarchical scan: A) tile sums, B) scan tile sums, C) tile scan + dinv
__global__ void scanA_kernel(const int* __restrict__ counts, int* __restrict__ tileSums, int n) {
    int t = threadIdx.x;
    int i = blockIdx.x * SCAN_TILE + t;
    int v = (i < n) ? counts[i] : 0;
    int lane = t & 63;
#pragma unroll
    for (int off = 32; off > 0; off >>= 1) v += __shfl_down(v, off);
    __shared__ int ws[4];
    if (lane == 0) ws[t >> 6] = v;
    __syncthreads();
    if (t == 0) tileSums[blockIdx.x] = ws[0] + ws[1] + ws[2] + ws[3];
}

// single block, ntiles <= 256: exclusive scan in place, total at [ntiles]
__global__ void scanB_kernel(int* tileSums, int ntiles) {
    int t = threadIdx.x;
    int v = (t < ntiles) ? tileSums[t] : 0;
    int lane = t & 63, w = t >> 6;
    int x = v;
#pragma unroll
    for (int off = 1; off < 64; off <<= 1) {
        int y = __shfl_up(x, off);
        if (lane >= off) x += y;
    }
    __shared__ int ws[4];
    if (lane == 63) ws[w] = x;
    __syncthreads();
    int add = 0;
    for (int k = 0; k < w; ++k) add += ws[k];
    int incl = x + add;
    if (t < ntiles) tileSums[t] = incl - v;          // exclusive
    if (t == ntiles - 1) tileSums[ntiles] = incl;    // grand total
}

__global__ void scanC_kernel(const int* __restrict__ counts, const int* __restrict__ tileOff,
                             int* __restrict__ row_ptr, float* __restrict__ dinv, int n) {
    int t = threadIdx.x;
    int i = blockIdx.x * SCAN_TILE + t;
    int v = (i < n) ? counts[i] : 0;
    int lane = t & 63, w = t >> 6;
    int x = v;
#pragma unroll
    for (int off = 1; off < 64; off <<= 1) {
        int y = __shfl_up(x, off);
        if (lane >= off) x += y;
    }
    __shared__ int ws[4];
    if (lane == 63) ws[w] = x;
    __syncthreads();
    int add = tileOff[blockIdx.x];
    for (int k = 0; k < w; ++k) add += ws[k];
    if (i < n) {
        row_ptr[i] = add + x - v;
        dinv[i] = rsqrtf((float)(v + 1));
    }
    if (i == n - 1) row_ptr[n] = add + x;            // total edge count
}

// ---------------------------------------------------------------------------
// gemm1: g1[row][c] = fp16( dinv[row] * (x @ W1)[row][c] )
// Block: 256 threads, tile 64 rows x 128 cols. Thread (tr=t>>4, tc=t&15)
// computes rows tr*4..+3, cols tc*8..+7 -> acc[4][8].
// x tile in LDS [64][132]; W1 staged per 32-k panel in LDS [32][132].
// Per k4-step: 12 ds_read_b128 vs 128 FMA -> FMA-issue-bound.
// ---------------------------------------------------------------------------
#define GB_ROWS 64
#define XPAD 132
__global__ __launch_bounds__(256) void gemm1_kernel(
        const float* __restrict__ x, const float* __restrict__ W1,
        const float* __restrict__ dinv, __half* __restrict__ g1, int n) {
    __shared__ float xs[GB_ROWS][XPAD];   // 33.8 KB
    __shared__ float ws[32][XPAD];        // 16.9 KB
    int t = threadIdx.x;
    int row0 = blockIdx.x * GB_ROWS;

    // stage x tile (coalesced float4, zero-pad rows >= n)
#pragma unroll
    for (int i = 0; i < 8; ++i) {
        int f = t + i * 256;              // float4 index within 64x128 tile
        int r = f >> 5, kq = f & 31;
        float4 v = make_float4(0.f, 0.f, 0.f, 0.f);
        if (row0 + r < n)
            v = *(const float4*)(x + (size_t)(row0 + r) * DIM + kq * 4);
        *(float4*)&xs[r][kq * 4] = v;
    }

    int tr = t >> 4;          // 0..15 -> rows tr*4..tr*4+3
    int tc = t & 15;          // cols tc*8..tc*8+7
    float acc[4][8];
#pragma unroll
    for (int i = 0; i < 4; ++i)
#pragma unroll
        for (int j = 0; j < 8; ++j) acc[i][j] = 0.f;

    for (int p = 0; p < 4; ++p) {         // 4 panels of 32 k
        __syncthreads();                  // xs ready / prior ws consumed
#pragma unroll
        for (int i = 0; i < 4; ++i) {
            int f = t + i * 256;          // float4 index within 32x128 panel
            int kk = f >> 5, kq = f & 31;
            *(float4*)&ws[kk][kq * 4] =
                *(const float4*)(W1 + (size_t)(p * 32 + kk) * DIM + kq * 4);
        }
        __syncthreads();
#pragma unroll 2
        for (int k4 = 0; k4 < 8; ++k4) {
            float4 xv[4];
#pragma unroll
            for (int i = 0; i < 4; ++i)
                xv[i] = *(const float4*)&xs[tr * 4 + i][p * 32 + k4 * 4];  // FIX: + p*32
            float4 wv[4][2];
#pragma unroll
            for (int kk = 0; kk < 4; ++kk) {
                wv[kk][0] = *(const float4*)&ws[k4 * 4 + kk][tc * 8];
                wv[kk][1] = *(const float4*)&ws[k4 * 4 + kk][tc * 8 + 4];
            }
            const float* xf = (const float*)&xv[0];   // [i*4 + kk]
            const float* wf = (const float*)&wv[0][0];// [kk*8 + j]
#pragma unroll
            for (int kk = 0; kk < 4; ++kk)
#pragma unroll
                for (int i = 0; i < 4; ++i) {
                    float xe = xf[i * 4 + kk];
#pragma unroll
                    for (int j = 0; j < 8; ++j)
                        acc[i][j] = fmaf(xe, wf[kk * 8 + j], acc[i][j]);
                }
        }
    }

    // epilogue: scale by dinv, convert fp16, store (16B per row per thread)
#pragma unroll
    for (int i = 0; i < 4; ++i) {
        int row = row0 + tr * 4 + i;
        if (row < n) {
            float dv = dinv[row];
            __half2 h4[4];
#pragma unroll
            for (int j = 0; j < 4; ++j)
                h4[j] = __floats2half2_rn(acc[i][2 * j] * dv, acc[i][2 * j + 1] * dv);
            *(float4*)((__half*)g1 + (size_t)row * DIM + tc * 8) = *(float4*)h4;
        }
    }
}

// One WAVE per dst node, lane owns 2 features (half2 = 4B; 256B/edge wave-wide).
// row_ptr/col_idx reads are wave-uniform -> scalarized (s_load), no shfl
// broadcast. 8 edges in flight per iteration, pairwise sums.
__global__ void agg1_kernel(const __half* __restrict__ g1, const int* __restrict__ row_ptr,
                            const int* __restrict__ col_idx, const float* __restrict__ dinv,
                            const float* __restrict__ b1, const float* __restrict__ W2,
                            float* __restrict__ g2, int n) {
    int lane = threadIdx.x & 63;
    int wid  = threadIdx.x >> 6;              // 0..3
    int d = blockIdx.x * 4 + wid;
    if (d >= n) return;
    const __half2* base = (const __half2*)g1 + lane;   // [n][64] half2
    float2 vf = __half22float2(base[d * 64]);          // self loop
    float acc0 = vf.x, acc1 = vf.y;
    int beg = __builtin_amdgcn_readfirstlane(row_ptr[d]);
    int end = __builtin_amdgcn_readfirstlane(row_ptr[d + 1]);
    int j = beg;
    for (; j + 8 <= end; j += 8) {
        int s0 = col_idx[j + 0], s1 = col_idx[j + 1];
        int s2 = col_idx[j + 2], s3 = col_idx[j + 3];
        int s4 = col_idx[j + 4], s5 = col_idx[j + 5];
        int s6 = col_idx[j + 6], s7 = col_idx[j + 7];
        __half2 h0 = base[s0 * 64], h1 = base[s1 * 64];
        __half2 h2 = base[s2 * 64], h3 = base[s3 * 64];
        __half2 h4 = base[s4 * 64], h5 = base[s5 * 64];
        __half2 h6 = base[s6 * 64], h7 = base[s7 * 64];
        float2 u0 = __half22float2(h0), u1 = __half22float2(h1);
        float2 u2 = __half22float2(h2), u3 = __half22float2(h3);
        float2 u4 = __half22float2(h4), u5 = __half22float2(h5);
        float2 u6 = __half22float2(h6), u7 = __half22float2(h7);
        acc0 += ((u0.x + u1.x) + (u2.x + u3.x)) + ((u4.x + u5.x) + (u6.x + u7.x));
        acc1 += ((u0.y + u1.y) + (u2.y + u3.y)) + ((u4.y + u5.y) + (u6.y + u7.y));
    }
    for (; j < end; ++j) {
        float2 u = __half22float2(base[col_idx[j] * 64]);
        acc0 += u.x; acc1 += u.y;
    }
    float dv = dinv[d];
    int f0 = lane * 2, f1 = f0 + 1;
    float h0 = fmaxf(dv * acc0 + b1[f0], 0.f);
    float h1 = fmaxf(dv * acc1 + b1[f1], 0.f);
    float z0 = fmaf(h1, W2[f1 * 2 + 0], h0 * W2[f0 * 2 + 0]);
    float z1 = fmaf(h1, W2[f1 * 2 + 1], h0 * W2[f0 * 2 + 1]);
#pragma unroll
    for (int off = 32; off > 0; off >>= 1) {
        z0 += __shfl_down(z0, off);
        z1 += __shfl_down(z1, off);
    }
    if (lane == 0) {
        g2[d * 2 + 0] = dv * z0;
        g2[d * 2 + 1] = dv * z1;
    }
}

// One WAVE per dst node, lane per edge (parallel gather), shuffle reduce,
// then bias + log_softmax on lane 0.
__global__ void agg2_kernel(const float* __restrict__ g2, const int* __restrict__ row_ptr,
                            const int* __restrict__ col_idx, const float* __restrict__ dinv,
                            const float* __restrict__ b2, float* __restrict__ out, int n) {
    int lane = threadIdx.x & 63;
    int wid  = threadIdx.x >> 6;
    int d = blockIdx.x * 4 + wid;
    if (d >= n) return;
    int beg = __builtin_amdgcn_readfirstlane(row_ptr[d]);
    int end = __builtin_amdgcn_readfirstlane(row_ptr[d + 1]);
    float a0 = 0.f, a1 = 0.f;
    const float2* g2v = (const float2*)g2;
    for (int j0 = beg; j0 < end; j0 += 64) {
        int j = j0 + lane;
        if (j < end) {
            float2 v = g2v[col_idx[j]];
            a0 += v.x; a1 += v.y;
        }
    }
#pragma unroll
    for (int off = 32; off > 0; off >>= 1) {
        a0 += __shfl_down(a0, off);
        a1 += __shfl_down(a1, off);
    }
    if (lane == 0) {
        float2 self = g2v[d];
        float dv = dinv[d];
        float z0 = dv * (a0 + self.x) + b2[0];
        float z1 = dv * (a1 + self.y) + b2[1];
        float m = fmaxf(z0, z1);
        float l = m + logf(expf(z0 - m) + expf(z1 - m));
        out[d * 2 + 0] = z0 - l;
        out[d * 2 + 1] = z1 - l;
    }
}

extern "C" void kernel_launch(void* const* d_in, const int* in_sizes, int n_in,
                              void* d_out, int out_size, void* d_ws, size_t ws_size,
                              hipStream_t stream) {
    const float* x  = (const float*)d_in[0];
    const int*   ei = (const int*)d_in[1];
    const float* W1 = (const float*)d_in[2];
    const float* b1 = (const float*)d_in[3];
    const float* W2 = (const float*)d_in[4];
    const float* b2 = (const float*)d_in[5];
    float* out = (float*)d_out;

    int n = in_sizes[0] / DIM;   // 50000
    int e = in_sizes[1] / 2;     // 800000
    int ntiles = (n + SCAN_TILE - 1) / SCAN_TILE;   // 196

    char* wsp = (char*)d_ws;
    size_t used = 0;
    auto alloc = [&](size_t bytes) {
        char* p = wsp + used;
        used += (bytes + 255) & ~(size_t)255;
        return p;
    };
    int*    flag     = (int*)alloc(sizeof(int));
    int*    counts   = (int*)alloc((size_t)n * 4);
    int*    cursor   = (int*)alloc((size_t)n * 4);
    int*    row_ptr  = (int*)alloc((size_t)(n + 1) * 4);
    int*    tileSums = (int*)alloc((size_t)(ntiles + 1) * 4);
    float*  dinv     = (float*)alloc((size_t)n * 4);
    int*    col_idx  = (int*)alloc((size_t)e * 4);
    __half* g1       = (__half*)alloc((size_t)n * DIM * 2);
    float*  g2       = (float*)alloc((size_t)n * 2 * 4);

    size_t per_e = ((size_t)e * 4 + 255) & ~(size_t)255;
    bool ticket_path = (used + 3 * per_e <= ws_size);
    int *s32 = nullptr, *d32 = nullptr, *ticket = nullptr;
    if (ticket_path) {
        s32    = (int*)alloc((size_t)e * 4);
        d32    = (int*)alloc((size_t)e * 4);
        ticket = (int*)alloc((size_t)e * 4);
    }

    const int tb = 256;
    int eblk = (e + tb - 1) / tb;
    init_detect_kernel<<<(n + tb - 1) / tb, tb, 0, stream>>>(ei, counts, cursor, flag, n);
    if (ticket_path)
        count_ticket_kernel<<<eblk, tb, 0, stream>>>(ei, flag, counts, s32, d32, ticket, e);
    else
        count_kernel<<<eblk, tb, 0, stream>>>(ei, flag, counts, e);
    scanA_kernel<<<ntiles, SCAN_TILE, 0, stream>>>(counts, tileSums, n);
    scanB_kernel<<<1, 256, 0, stream>>>(tileSums, ntiles);
    scanC_kernel<<<ntiles, SCAN_TILE, 0, stream>>>(counts, tileSums, row_ptr, dinv, n);
    if (ticket_path)
        fill_ticket_kernel<<<eblk, tb, 0, stream>>>(s32, d32, ticket, row_ptr, col_idx, e);
    else
        fill_kernel<<<eblk, tb, 0, stream>>>(ei, flag, row_ptr, cursor, col_idx, e);
    gemm1_kernel<<<(n + GB_ROWS - 1) / GB_ROWS, 256, 0, stream>>>(x, W1, dinv, g1, n);
    agg1_kernel<<<(n + 3) / 4, 256, 0, stream>>>(g1, row_ptr, col_idx, dinv, b1, W2, g2, n);
    agg2_kernel<<<(n + 3) / 4, 256, 0, stream>>>(g2, row_ptr, col_idx, dinv, b2, out, n);
}

// Round 7
// 129.250 us; speedup vs baseline: 2.3934x; 1.1216x over previous
//
#include <hip/hip_runtime.h>
#include <hip/hip_fp16.h>

// ---------------------------------------------------------------------------
// GCN forward: 2-layer, fused normalization.
//   deg[d] = in_degree(d) + 1 (self loop);  dinv = 1/sqrt(deg)
//   g1 = fp16( (x @ W1) .* dinv )           [f16 MFMA, f32 accum]
//   h  = relu(dinv[d] * (sum_{s->d} g1[s] + g1[d]) + b1)
//   g2 = dinv .* (h @ W2)                   (fused into agg1 epilogue)
//   z  = dinv[d] * (sum_{s->d} g2[s] + g2[d]) + b2
//   out = log_softmax(z)
// gemm1 via v_mfma_f32_16x16x32_f16: A/B frag outer=lane&15, k=(lane>>4)*8+j;
// C/D col=lane&15, row=(lane>>4)*4+reg. LDS XOR-swizzle ((row&7)<<4) kills the
// row-per-lane 16-way bank conflict. W1 transposed->f16 once in scanB's block.
// ---------------------------------------------------------------------------

#define DIM 128
#define SCAN_TILE 256

typedef _Float16 f16x8 __attribute__((ext_vector_type(8)));
typedef float f32x4 __attribute__((ext_vector_type(4)));

__device__ __forceinline__ int load_idx(const int* ei, long long pos, int is64) {
    if (is64) return (int)((const long long*)ei)[pos];
    return ei[pos];
}

// Per-block int64-vs-int32 detection: int64 edge_index has zero high words.
__device__ __forceinline__ int detect_is64(const int* __restrict__ ei, int e) {
    __shared__ int sflag;
    int t = threadIdx.x;
    int hv = (t < 32 && (2 * t + 1) < 2 * e) ? ei[2 * t + 1] : 0;
    unsigned long long nz = __ballot(hv != 0);
    if (t == 0) sflag = (nz == 0ULL) ? 1 : 0;
    __syncthreads();
    return sflag;
}

// Decode edges, count in-degree, hand out ticket (slot within dst row).
// dt packs dst (17 bits) | ticket<<17 (15 bits) -> fill needs no atomics.
__global__ void count_ticket_kernel(const int* __restrict__ ei, int* counts,
                                    int* __restrict__ s32, unsigned int* __restrict__ dt,
                                    int e) {
    int is64 = detect_is64(ei, e);
    int i = blockIdx.x * blockDim.x + threadIdx.x;
    if (i >= e) return;
    int s = load_idx(ei, i, is64);
    int d = load_idx(ei, (long long)e + i, is64);
    s32[i] = s;
    unsigned int tk = (unsigned int)atomicAdd(&counts[d], 1);
    dt[i] = (unsigned int)d | (tk << 17);
}

__global__ void fill_ticket_kernel(const int* __restrict__ s32, const unsigned int* __restrict__ dt,
                                   const int* __restrict__ row_ptr, int* __restrict__ col_idx,
                                   int e) {
    int i = blockIdx.x * blockDim.x + threadIdx.x;
    if (i >= e) return;
    unsigned int v = dt[i];
    int d = (int)(v & 0x1FFFFu);
    int tk = (int)(v >> 17);
    col_idx[row_ptr[d] + tk] = s32[i];
}

// Fallback path (small workspace): atomic cursor fill.
__global__ void count_kernel(const int* __restrict__ ei, int* counts, int e) {
    int is64 = detect_is64(ei, e);
    int i = blockIdx.x * blockDim.x + threadIdx.x;
    if (i >= e) return;
    int d = load_idx(ei, (long long)e + i, is64);
    atomicAdd(&counts[d], 1);
}

__global__ void fill_kernel(const int* __restrict__ ei, const int* __restrict__ row_ptr,
                            int* cursor, int* __restrict__ col_idx, int e) {
    int is64 = detect_is64(ei, e);
    int i = blockIdx.x * blockDim.x + threadIdx.x;
    if (i >= e) return;
    int s = load_idx(ei, i, is64);
    int d = load_idx(ei, (long long)e + i, is64);
    int pos = row_ptr[d] + atomicAdd(&cursor[d], 1);
    col_idx[pos] = s;
}

// ---- hierarchical scan: A) tile sums, B) scan tile sums (+W1 prep), C) tile scan + dinv
__global__ void scanA_kernel(const int* __restrict__ counts, int* __restrict__ tileSums, int n) {
    int t = threadIdx.x;
    int i = blockIdx.x * SCAN_TILE + t;
    int v = (i < n) ? counts[i] : 0;
    int lane = t & 63;
#pragma unroll
    for (int off = 32; off > 0; off >>= 1) v += __shfl_down(v, off);
    __shared__ int ws[4];
    if (lane == 0) ws[t >> 6] = v;
    __syncthreads();
    if (t == 0) tileSums[blockIdx.x] = ws[0] + ws[1] + ws[2] + ws[3];
}

// single block: exclusive-scan tileSums (ntiles <= 256) AND prepare
// W1T[col][k] = f16(W1[k][col]) for the MFMA gemm (block otherwise idle).
#define TLP 136   // padded k-stride (halfs); 136*2=272B, 16B-aligned chunks
__global__ void scanB_w1prep_kernel(int* tileSums, int ntiles,
                                    const float* __restrict__ W1, __half* __restrict__ W1T) {
    int t = threadIdx.x;
    int v = (t < ntiles) ? tileSums[t] : 0;
    int lane = t & 63, w = t >> 6;
    int x = v;
#pragma unroll
    for (int off = 1; off < 64; off <<= 1) {
        int y = __shfl_up(x, off);
        if (lane >= off) x += y;
    }
    __shared__ int ws[4];
    if (lane == 63) ws[w] = x;
    __syncthreads();
    int add = 0;
    for (int k = 0; k < w; ++k) add += ws[k];
    int incl = x + add;
    if (t < ntiles) tileSums[t] = incl - v;          // exclusive
    if (t == ntiles - 1) tileSums[ntiles] = incl;    // grand total

    // --- W1 transpose+convert via LDS ---
    __shared__ __half tl[DIM * TLP];
    for (int i = 0; i < 64; ++i) {
        int f = t + i * 256;             // over 128x128, c fastest -> coalesced
        int k = f >> 7, c = f & 127;
        tl[c * TLP + k] = __float2half(W1[f]);
    }
    __syncthreads();
    for (int i = 0; i < 8; ++i) {
        int f = t + i * 256;             // 2048 16B chunks of W1T [128][128]
        int c = f >> 4, kc = f & 15;
        *(float4*)((char*)W1T + (size_t)f * 16) =
            *(float4*)((char*)tl + (size_t)c * (TLP * 2) + kc * 16);
    }
}

__global__ void scanC_kernel(const int* __restrict__ counts, const int* __restrict__ tileOff,
                             int* __restrict__ row_ptr, float* __restrict__ dinv, int n) {
    int t = threadIdx.x;
    int i = blockIdx.x * SCAN_TILE + t;
    int v = (i < n) ? counts[i] : 0;
    int lane = t & 63, w = t >> 6;
    int x = v;
#pragma unroll
    for (int off = 1; off < 64; off <<= 1) {
        int y = __shfl_up(x, off);
        if (lane >= off) x += y;
    }
    __shared__ int ws[4];
    if (lane == 63) ws[w] = x;
    __syncthreads();
    int add = tileOff[blockIdx.x];
    for (int k = 0; k < w; ++k) add += ws[k];
    if (i < n) {
        row_ptr[i] = add + x - v;
        dinv[i] = rsqrtf((float)(v + 1));
    }
    if (i == n - 1) row_ptr[n] = add + x;            // total edge count
}

// ---------------------------------------------------------------------------
// gemm1 (MFMA): 128 rows x 128 cols per block, 4 waves, wave owns 32 rows.
// xs: x tile as f16 [128][128] row-major, XOR-swizzled; wt: W1T [col][k] f16,
// same swizzle. Per wave: 4 k-tiles x (2 A-frag + 8 B-frag reads, 16 MFMA).
// ---------------------------------------------------------------------------
#define GR 128
__global__ __launch_bounds__(256) void gemm1_kernel(
        const float* __restrict__ x, const __half* __restrict__ W1T,
        const float* __restrict__ dinv, __half* __restrict__ g1, int n) {
    __shared__ short xs[GR * DIM];    // 32 KB
    __shared__ short wt[DIM * DIM];   // 32 KB
    int t = threadIdx.x;
    int row0 = blockIdx.x * GR;

    // stage W1T (already f16 [col][k]): 2048 x 16B, swizzled write
#pragma unroll
    for (int i = 0; i < 8; ++i) {
        int f = t + i * 256;
        int col = f >> 4, kc = f & 15;
        unsigned int byte = (unsigned)(col * 256 + kc * 16);
        byte ^= (unsigned)((col & 7) << 4);
        *(float4*)((char*)wt + byte) = *(const float4*)((const char*)W1T + (size_t)f * 16);
    }
    // stage x tile f32 -> f16: 4096 float4 chunks -> 8B swizzled writes
#pragma unroll
    for (int i = 0; i < 16; ++i) {
        int f = t + i * 256;
        int r = f >> 5, c4 = f & 31;
        float4 v = make_float4(0.f, 0.f, 0.f, 0.f);
        if (row0 + r < n)
            v = *(const float4*)(x + (size_t)(row0 + r) * DIM + c4 * 4);
        __half2 p01 = __floats2half2_rn(v.x, v.y);
        __half2 p23 = __floats2half2_rn(v.z, v.w);
        float2 pk;
        ((__half2*)&pk)[0] = p01;
        ((__half2*)&pk)[1] = p23;
        unsigned int byte = (unsigned)(r * 256 + c4 * 8);
        byte ^= (unsigned)((r & 7) << 4);
        *(float2*)((char*)xs + byte) = pk;
    }
    __syncthreads();

    int w  = t >> 6;     // wave 0..3 -> rows w*32 .. w*32+31
    int l  = t & 63;
    int lr = l & 15;     // A row / B col within fragment
    int lg = l >> 4;     // k-group (8 contiguous k each)

    f32x4 acc[2][8];
#pragma unroll
    for (int m = 0; m < 2; ++m)
#pragma unroll
        for (int cf = 0; cf < 8; ++cf) acc[m][cf] = (f32x4){0.f, 0.f, 0.f, 0.f};

#pragma unroll
    for (int kt = 0; kt < 4; ++kt) {
        int kByte = kt * 64 + lg * 16;
        f16x8 a[2];
#pragma unroll
        for (int m = 0; m < 2; ++m) {
            int row = w * 32 + m * 16 + lr;
            unsigned int byte = (unsigned)(row * 256 + kByte);
            byte ^= (unsigned)((row & 7) << 4);
            a[m] = *(const f16x8*)((const char*)xs + byte);
        }
#pragma unroll
        for (int cf = 0; cf < 8; ++cf) {
            int col = cf * 16 + lr;
            unsigned int byte = (unsigned)(col * 256 + kByte);
            byte ^= (unsigned)((col & 7) << 4);
            f16x8 b = *(const f16x8*)((const char*)wt + byte);
            acc[0][cf] = __builtin_amdgcn_mfma_f32_16x16x32_f16(a[0], b, acc[0][cf], 0, 0, 0);
            acc[1][cf] = __builtin_amdgcn_mfma_f32_16x16x32_f16(a[1], b, acc[1][cf], 0, 0, 0);
        }
    }

    // epilogue: C/D frag row=(l>>4)*4+reg, col=lane&15
    float dv[2][4];
#pragma unroll
    for (int m = 0; m < 2; ++m)
#pragma unroll
        for (int r4 = 0; r4 < 4; ++r4) {
            int row = row0 + w * 32 + m * 16 + lg * 4 + r4;
            dv[m][r4] = (row < n) ? dinv[row] : 0.f;
        }
#pragma unroll
    for (int m = 0; m < 2; ++m)
#pragma unroll
        for (int cf = 0; cf < 8; ++cf)
#pragma unroll
            for (int r4 = 0; r4 < 4; ++r4) {
                int row = row0 + w * 32 + m * 16 + lg * 4 + r4;
                if (row < n) {
                    int col = cf * 16 + lr;
                    g1[(size_t)row * DIM + col] = __float2half(acc[m][cf][r4] * dv[m][r4]);
                }
            }
}

// One WAVE per dst node, lane owns 2 features (half2 = 4B; 256B/edge wave-wide).
// row_ptr/col_idx reads are wave-uniform -> scalarized. 8 edges in flight.
__global__ void agg1_kernel(const __half* __restrict__ g1, const int* __restrict__ row_ptr,
                            const int* __restrict__ col_idx, const float* __restrict__ dinv,
                            const float* __restrict__ b1, const float* __restrict__ W2,
                            float* __restrict__ g2, int n) {
    int lane = threadIdx.x & 63;
    int wid  = threadIdx.x >> 6;              // 0..3
    int d = blockIdx.x * 4 + wid;
    if (d >= n) return;
    const __half2* base = (const __half2*)g1 + lane;   // [n][64] half2
    float2 vf = __half22float2(base[d * 64]);          // self loop
    float acc0 = vf.x, acc1 = vf.y;
    int beg = __builtin_amdgcn_readfirstlane(row_ptr[d]);
    int end = __builtin_amdgcn_readfirstlane(row_ptr[d + 1]);
    int j = beg;
    for (; j + 8 <= end; j += 8) {
        int s0 = col_idx[j + 0], s1 = col_idx[j + 1];
        int s2 = col_idx[j + 2], s3 = col_idx[j + 3];
        int s4 = col_idx[j + 4], s5 = col_idx[j + 5];
        int s6 = col_idx[j + 6], s7 = col_idx[j + 7];
        __half2 h0 = base[s0 * 64], h1 = base[s1 * 64];
        __half2 h2 = base[s2 * 64], h3 = base[s3 * 64];
        __half2 h4 = base[s4 * 64], h5 = base[s5 * 64];
        __half2 h6 = base[s6 * 64], h7 = base[s7 * 64];
        float2 u0 = __half22float2(h0), u1 = __half22float2(h1);
        float2 u2 = __half22float2(h2), u3 = __half22float2(h3);
        float2 u4 = __half22float2(h4), u5 = __half22float2(h5);
        float2 u6 = __half22float2(h6), u7 = __half22float2(h7);
        acc0 += ((u0.x + u1.x) + (u2.x + u3.x)) + ((u4.x + u5.x) + (u6.x + u7.x));
        acc1 += ((u0.y + u1.y) + (u2.y + u3.y)) + ((u4.y + u5.y) + (u6.y + u7.y));
    }
    for (; j < end; ++j) {
        float2 u = __half22float2(base[col_idx[j] * 64]);
        acc0 += u.x; acc1 += u.y;
    }
    float dv = dinv[d];
    int f0 = lane * 2, f1 = f0 + 1;
    float h0 = fmaxf(dv * acc0 + b1[f0], 0.f);
    float h1 = fmaxf(dv * acc1 + b1[f1], 0.f);
    float z0 = fmaf(h1, W2[f1 * 2 + 0], h0 * W2[f0 * 2 + 0]);
    float z1 = fmaf(h1, W2[f1 * 2 + 1], h0 * W2[f0 * 2 + 1]);
#pragma unroll
    for (int off = 32; off > 0; off >>= 1) {
        z0 += __shfl_down(z0, off);
        z1 += __shfl_down(z1, off);
    }
    if (lane == 0) {
        g2[d * 2 + 0] = dv * z0;
        g2[d * 2 + 1] = dv * z1;
    }
}

// One WAVE per dst node, lane per edge (parallel gather), shuffle reduce,
// then bias + log_softmax on lane 0.
__global__ void agg2_kernel(const float* __restrict__ g2, const int* __restrict__ row_ptr,
                            const int* __restrict__ col_idx, const float* __restrict__ dinv,
                            const float* __restrict__ b2, float* __restrict__ out, int n) {
    int lane = threadIdx.x & 63;
    int wid  = threadIdx.x >> 6;
    int d = blockIdx.x * 4 + wid;
    if (d >= n) return;
    int beg = __builtin_amdgcn_readfirstlane(row_ptr[d]);
    int end = __builtin_amdgcn_readfirstlane(row_ptr[d + 1]);
    float a0 = 0.f, a1 = 0.f;
    const float2* g2v = (const float2*)g2;
    for (int j0 = beg; j0 < end; j0 += 64) {
        int j = j0 + lane;
        if (j < end) {
            float2 v = g2v[col_idx[j]];
            a0 += v.x; a1 += v.y;
        }
    }
#pragma unroll
    for (int off = 32; off > 0; off >>= 1) {
        a0 += __shfl_down(a0, off);
        a1 += __shfl_down(a1, off);
    }
    if (lane == 0) {
        float2 self = g2v[d];
        float dv = dinv[d];
        float z0 = dv * (a0 + self.x) + b2[0];
        float z1 = dv * (a1 + self.y) + b2[1];
        float m = fmaxf(z0, z1);
        float l = m + logf(expf(z0 - m) + expf(z1 - m));
        out[d * 2 + 0] = z0 - l;
        out[d * 2 + 1] = z1 - l;
    }
}

extern "C" void kernel_launch(void* const* d_in, const int* in_sizes, int n_in,
                              void* d_out, int out_size, void* d_ws, size_t ws_size,
                              hipStream_t stream) {
    const float* x  = (const float*)d_in[0];
    const int*   ei = (const int*)d_in[1];
    const float* W1 = (const float*)d_in[2];
    const float* b1 = (const float*)d_in[3];
    const float* W2 = (const float*)d_in[4];
    const float* b2 = (const float*)d_in[5];
    float* out = (float*)d_out;

    int n = in_sizes[0] / DIM;   // 50000
    int e = in_sizes[1] / 2;     // 800000
    int ntiles = (n + SCAN_TILE - 1) / SCAN_TILE;   // 196

    char* wsp = (char*)d_ws;
    size_t used = 0;
    auto alloc = [&](size_t bytes) {
        char* p = wsp + used;
        used += (bytes + 255) & ~(size_t)255;
        return p;
    };
    int*    counts   = (int*)alloc((size_t)n * 4);
    int*    cursor   = (int*)alloc((size_t)n * 4);   // fallback path only
    int*    row_ptr  = (int*)alloc((size_t)(n + 1) * 4);
    int*    tileSums = (int*)alloc((size_t)(ntiles + 1) * 4);
    float*  dinv     = (float*)alloc((size_t)n * 4);
    int*    col_idx  = (int*)alloc((size_t)e * 4);
    __half* g1       = (__half*)alloc((size_t)n * DIM * 2);
    float*  g2       = (float*)alloc((size_t)n * 2 * 4);
    __half* W1T      = (__half*)alloc((size_t)DIM * DIM * 2);
    size_t zero_span = (size_t)((char*)row_ptr - (char*)counts);   // counts+cursor

    size_t per_e = ((size_t)e * 4 + 255) & ~(size_t)255;
    bool ticket_path = (used + 2 * per_e <= ws_size);
    int *s32 = nullptr; unsigned int* dt = nullptr;
    if (ticket_path) {
        s32 = (int*)alloc((size_t)e * 4);
        dt  = (unsigned int*)alloc((size_t)e * 4);
    }

    const int tb = 256;
    int eblk = (e + tb - 1) / tb;
    hipMemsetAsync(counts, 0, zero_span, stream);
    if (ticket_path)
        count_ticket_kernel<<<eblk, tb, 0, stream>>>(ei, counts, s32, dt, e);
    else
        count_kernel<<<eblk, tb, 0, stream>>>(ei, counts, e);
    scanA_kernel<<<ntiles, SCAN_TILE, 0, stream>>>(counts, tileSums, n);
    scanB_w1prep_kernel<<<1, 256, 0, stream>>>(tileSums, ntiles, W1, W1T);
    scanC_kernel<<<ntiles, SCAN_TILE, 0, stream>>>(counts, tileSums, row_ptr, dinv, n);
    if (ticket_path)
        fill_ticket_kernel<<<eblk, tb, 0, stream>>>(s32, dt, row_ptr, col_idx, e);
    else
        fill_kernel<<<eblk, tb, 0, stream>>>(ei, row_ptr, cursor, col_idx, e);
    gemm1_kernel<<<(n + GR - 1) / GR, 256, 0, stream>>>(x, W1T, dinv, g1, n);
    agg1_kernel<<<(n + 3) / 4, 256, 0, stream>>>(g1, row_ptr, col_idx, dinv, b1, W2, g2, n);
    agg2_kernel<<<(n + 3) / 4, 256, 0, stream>>>(g2, row_ptr, col_idx, dinv, b2, out, n);
}